// Round 1
// baseline (308.268 us; speedup 1.0000x reference)
//
#include <hip/hip_runtime.h>

// LocalStructureAnalyse: structure tensor + closed-form 2x2 eigendecomposition.
// x: (16,1,1536,1536) fp32.  Outputs (concatenated planes, each (16,1536,1536) fp32):
//   lambda1, lambda2, e11, e12, e21, e22   (lambda1 = smaller-|.| eigenvalue, ReLU'd)

constexpr int N = 16, H = 1536, W = 1536;
constexpr int TH = 16, TW = 128;          // output tile per block
constexpr int XR = TH + 3, XC = TW + 3;   // x stage tile 19 x 131 (halo -2..+1)
constexpr int PR = TH + 2, PC = TW + 2;   // product tile 18 x 130 (halo -1..+1)

__global__ __launch_bounds__(256)
void lsa_kernel(const float* __restrict__ x, float* __restrict__ out) {
    __shared__ float Xs[XR][XC];
    __shared__ float Pxx[PR][PC];
    __shared__ float Pxy[PR][PC];
    __shared__ float Pyy[PR][PC];

    const int tj0 = blockIdx.x * TW;   // tile col origin
    const int ti0 = blockIdx.y * TH;   // tile row origin
    const int n   = blockIdx.z;
    const float* __restrict__ xn = x + (size_t)n * H * W;
    const int tid = threadIdx.x;

    // ---- stage x tile: rows [ti0-2, ti0+TH], cols [tj0-2, tj0+TW] ----
    for (int idx = tid; idx < XR * XC; idx += 256) {
        int r = idx / XC, c = idx % XC;
        int p = ti0 - 2 + r, q = tj0 - 2 + c;
        float v = 0.0f;
        if (p >= 0 && p < H && q >= 0 && q < W) v = xn[(size_t)p * W + q];
        Xs[r][c] = v;
    }
    __syncthreads();

    // ---- gradient products at (p,q) = (ti0-1+rp, tj0-1+cp) ----
    // gx(p,q) = x(p, q==0?1:q-1) - x(p,q);  gy(p,q) = x(p==0?1:p-1, q) - x(p,q)
    // out-of-image window taps contribute 0 (zero padding of the conv).
    for (int idx = tid; idx < PR * PC; idx += 256) {
        int rp = idx / PC, cp = idx % PC;
        int p = ti0 - 1 + rp, q = tj0 - 1 + cp;
        float gxx = 0.0f, gxy = 0.0f, gyy = 0.0f;
        if (p >= 0 && p < H && q >= 0 && q < W) {
            float xc = Xs[rp + 1][cp + 1];
            float xl = (q == 0) ? Xs[rp + 1][cp + 2] : Xs[rp + 1][cp];
            float xu = (p == 0) ? Xs[rp + 2][cp + 1] : Xs[rp][cp + 1];
            float gx = xl - xc;
            float gy = xu - xc;
            gxx = gx * gx; gxy = gx * gy; gyy = gy * gy;
        }
        Pxx[rp][cp] = gxx;
        Pxy[rp][cp] = gxy;
        Pyy[rp][cp] = gyy;
    }
    __syncthreads();

    // ---- 3x3 box sum + eigendecomposition + store 6 planes ----
    const size_t PLANE = (size_t)N * H * W;
    for (int idx = tid; idx < TH * TW; idx += 256) {
        int ri = idx / TW, cj = idx % TW;
        float sxx = 0.0f, sxy = 0.0f, syy = 0.0f;
#pragma unroll
        for (int di = 0; di < 3; ++di) {
#pragma unroll
            for (int dj = 0; dj < 3; ++dj) {
                sxx += Pxx[ri + di][cj + dj];
                sxy += Pxy[ri + di][cj + dj];
                syy += Pyy[ri + di][cj + dj];
            }
        }
        const float inv9 = 1.0f / 9.0f;
        float Axx = sxx * inv9, Axy = sxy * inv9, Ayy = syy * inv9;

        float T  = Axx + Ayy;
        float Dd = Axx * Ayy - Axy * Axy;
        float s  = sqrtf(fabsf(T * T * 0.25f - Dd));
        float l1 = T * 0.5f + s;
        float l2 = T * 0.5f - s;

        float e11 = l1 - Ayy, e12 = Axy;
        float e21 = l2 - Ayy, e22 = Axy;
        bool small = fabsf(Axy) < 1e-9f;
        e11 = small ? 1.0f : e11;
        e12 = small ? 0.0f : e12;
        e21 = small ? 0.0f : e21;
        e22 = small ? 1.0f : e22;

        bool lt = fabsf(l1) < fabsf(l2);
        float lam1 = lt ? l1 : l2;
        float lam2 = lt ? l2 : l1;
        float E11 = lt ? e11 : e21;
        float E12 = lt ? e12 : e22;
        float E21 = lt ? e21 : e11;
        float E22 = lt ? e22 : e12;
        lam1 = fmaxf(lam1, 0.0f);   // ReLU on lambda1 only (ref typo keeps lambda2 raw)

        size_t o = (size_t)n * H * W + (size_t)(ti0 + ri) * W + (size_t)(tj0 + cj);
        out[o]             = lam1;
        out[PLANE + o]     = lam2;
        out[2 * PLANE + o] = E11;
        out[3 * PLANE + o] = E12;
        out[4 * PLANE + o] = E21;
        out[5 * PLANE + o] = E22;
    }
}

extern "C" void kernel_launch(void* const* d_in, const int* in_sizes, int n_in,
                              void* d_out, int out_size, void* d_ws, size_t ws_size,
                              hipStream_t stream) {
    const float* x = (const float*)d_in[0];
    // d_in[1] is the 3x3 weight = 1/9 everywhere (fixed by setup); folded into inv9.
    float* out = (float*)d_out;

    dim3 grid(W / TW, H / TH, N);   // 12 x 96 x 16
    dim3 block(256);
    lsa_kernel<<<grid, block, 0, stream>>>(x, out);
}

// Round 3
// 208.549 us; speedup vs baseline: 1.4782x; 1.4782x over previous
//
#include <hip/hip_runtime.h>

// LocalStructureAnalyse: structure tensor + closed-form 2x2 eigendecomposition.
// x: (16,1,1536,1536) fp32.  Out: 6 planes (16,1536,1536) fp32 concatenated:
//   lambda1(ReLU), lambda2, e11, e12, e21, e22.
//
// R3 = R2 design with clang ext_vector types for nontemporal float4 stores.
//   P1: stage x tile (19 rows x 136 cols, float4-aligned) into LDS
//   P2: vertical 3-tap column sums of (gx*gx, gx*gy, gy*gy) -> C arrays in LDS
//   P3: horizontal 3-tap via ds_read_b128/b64, eig, 6x float4 nontemporal stores

typedef float f32x4 __attribute__((ext_vector_type(4)));
typedef float f32x2 __attribute__((ext_vector_type(2)));

constexpr int N = 16, H = 1536, W = 1536;
constexpr int TH = 16, TW = 128;      // output tile
constexpr int XR = TH + 3;            // x rows: ti0-2 .. ti0+16
constexpr int XQ = 34;                // float4s per x row: cols tj0-4 .. tj0+131
constexpr int XC = XQ * 4;            // 136
constexpr int CN = 130;               // colsum cols used: c = -1 .. 128
constexpr int CC = 132;               // padded stride (16B-aligned rows)

__global__ __launch_bounds__(256, 4)
void lsa_kernel(const float* __restrict__ x, float* __restrict__ out) {
    __shared__ float Xs[XR][XC];
    __shared__ float Cxx[TH][CC], Cxy[TH][CC], Cyy[TH][CC];

    const int tj0 = blockIdx.x * TW;
    const int ti0 = blockIdx.y * TH;
    const int n   = blockIdx.z;
    const float* __restrict__ xn = x + (size_t)n * (H * W);
    const int tid = threadIdx.x;
    const int rsub = tid >> 5;        // 0..7
    const int csub = tid & 31;        // 0..31

    // ---- P1: stage x tile. Rows ti0-2..ti0+16, cols tj0-4..tj0+131 ----
    for (int rr = rsub; rr < XR; rr += 8) {
        const int p = ti0 - 2 + rr;
        const float* rowp = xn + (size_t)p * W;
        const bool prow = (p >= 0) & (p < H);
        for (int cq = csub; cq < XQ; cq += 32) {
            const int qb = tj0 - 4 + 4 * cq;
            f32x4 v;
            if (prow && qb >= 0 && qb + 3 < W) {
                v = *reinterpret_cast<const f32x4*>(rowp + qb);
            } else {
                v.x = (prow && qb + 0 >= 0 && qb + 0 < W) ? rowp[qb + 0] : 0.f;
                v.y = (prow && qb + 1 >= 0 && qb + 1 < W) ? rowp[qb + 1] : 0.f;
                v.z = (prow && qb + 2 >= 0 && qb + 2 < W) ? rowp[qb + 2] : 0.f;
                v.w = (prow && qb + 3 >= 0 && qb + 3 < W) ? rowp[qb + 3] : 0.f;
            }
            *reinterpret_cast<f32x4*>(&Xs[rr][4 * cq]) = v;
        }
    }
    __syncthreads();

    // ---- P2: vertical 3-tap column sums of gradient products ----
    // C*[rr][ci] = sum_{d=-1..1} prod(ti0+rr+d, tj0+ci-1); zero-pad OOB taps.
    for (int rr = rsub; rr < TH; rr += 8) {
        const int P0 = ti0 + rr;
        for (int ci = csub; ci < CN; ci += 32) {
            const int q = tj0 + ci - 1;
            float sxx = 0.f, sxy = 0.f, syy = 0.f;
            if (q >= 0 && q < W) {
                const int cc = ci + 3;   // Xs col index for abs col q
#pragma unroll
                for (int d = -1; d <= 1; ++d) {
                    const int p = P0 + d;
                    if (p >= 0 && p < H) {
                        const int RR = rr + d + 2;  // Xs row index for abs row p
                        const float xc = Xs[RR][cc];
                        const float xl = (q == 0) ? Xs[RR][cc + 1] : Xs[RR][cc - 1];
                        const float xu = (p == 0) ? Xs[RR + 1][cc] : Xs[RR - 1][cc];
                        const float gx = xl - xc;
                        const float gy = xu - xc;
                        sxx += gx * gx; sxy += gx * gy; syy += gy * gy;
                    }
                }
            }
            Cxx[rr][ci] = sxx; Cxy[rr][ci] = sxy; Cyy[rr][ci] = syy;
        }
    }
    __syncthreads();

    // ---- P3: horizontal 3-tap + eig + stores (4 px per thread-iteration) ----
    const size_t HW = (size_t)H * W;
    const size_t PLANE = (size_t)N * HW;
    const int cj = 4 * csub;            // output col offset in tile, 16B-aligned
    const float inv9 = 1.0f / 9.0f;
    for (int rr = rsub; rr < TH; rr += 8) {
        const f32x4 a_xx = *reinterpret_cast<const f32x4*>(&Cxx[rr][cj]);
        const f32x2 b_xx = *reinterpret_cast<const f32x2*>(&Cxx[rr][cj + 4]);
        const f32x4 a_xy = *reinterpret_cast<const f32x4*>(&Cxy[rr][cj]);
        const f32x2 b_xy = *reinterpret_cast<const f32x2*>(&Cxy[rr][cj + 4]);
        const f32x4 a_yy = *reinterpret_cast<const f32x4*>(&Cyy[rr][cj]);
        const f32x2 b_yy = *reinterpret_cast<const f32x2*>(&Cyy[rr][cj + 4]);
        const float vxx[6] = {a_xx.x, a_xx.y, a_xx.z, a_xx.w, b_xx.x, b_xx.y};
        const float vxy[6] = {a_xy.x, a_xy.y, a_xy.z, a_xy.w, b_xy.x, b_xy.y};
        const float vyy[6] = {a_yy.x, a_yy.y, a_yy.z, a_yy.w, b_yy.x, b_yy.y};

        f32x4 o_l1, o_l2, o_e11, o_e12, o_e21, o_e22;
#pragma unroll
        for (int k = 0; k < 4; ++k) {
            const float Axx = (vxx[k] + vxx[k + 1] + vxx[k + 2]) * inv9;
            const float Axy = (vxy[k] + vxy[k + 1] + vxy[k + 2]) * inv9;
            const float Ayy = (vyy[k] + vyy[k + 1] + vyy[k + 2]) * inv9;

            const float T  = Axx + Ayy;
            const float Dd = Axx * Ayy - Axy * Axy;
            const float s  = sqrtf(fabsf(T * T * 0.25f - Dd));
            const float l1 = T * 0.5f + s;
            const float l2 = T * 0.5f - s;

            float e11 = l1 - Ayy, e12 = Axy;
            float e21 = l2 - Ayy, e22 = Axy;
            const bool small = fabsf(Axy) < 1e-9f;
            e11 = small ? 1.0f : e11;
            e12 = small ? 0.0f : e12;
            e21 = small ? 0.0f : e21;
            e22 = small ? 1.0f : e22;

            const bool lt = fabsf(l1) < fabsf(l2);
            o_l1[k]  = fmaxf(lt ? l1 : l2, 0.0f);  // ReLU only lambda1 (ref typo)
            o_l2[k]  = lt ? l2 : l1;
            o_e11[k] = lt ? e11 : e21;
            o_e12[k] = lt ? e12 : e22;
            o_e21[k] = lt ? e21 : e11;
            o_e22[k] = lt ? e22 : e12;
        }

        const size_t o = (size_t)n * HW + (size_t)(ti0 + rr) * W + (size_t)(tj0 + cj);
        __builtin_nontemporal_store(o_l1,  reinterpret_cast<f32x4*>(out + o));
        __builtin_nontemporal_store(o_l2,  reinterpret_cast<f32x4*>(out + PLANE + o));
        __builtin_nontemporal_store(o_e11, reinterpret_cast<f32x4*>(out + 2 * PLANE + o));
        __builtin_nontemporal_store(o_e12, reinterpret_cast<f32x4*>(out + 3 * PLANE + o));
        __builtin_nontemporal_store(o_e21, reinterpret_cast<f32x4*>(out + 4 * PLANE + o));
        __builtin_nontemporal_store(o_e22, reinterpret_cast<f32x4*>(out + 5 * PLANE + o));
    }
}

extern "C" void kernel_launch(void* const* d_in, const int* in_sizes, int n_in,
                              void* d_out, int out_size, void* d_ws, size_t ws_size,
                              hipStream_t stream) {
    const float* x = (const float*)d_in[0];
    // d_in[1] is the 3x3 weight, fixed to 1/9 by setup -> folded into inv9.
    float* out = (float*)d_out;

    dim3 grid(W / TW, H / TH, N);   // 12 x 96 x 16
    dim3 block(256);
    lsa_kernel<<<grid, block, 0, stream>>>(x, out);
}

// Round 4
// 181.942 us; speedup vs baseline: 1.6943x; 1.1462x over previous
//
#include <hip/hip_runtime.h>

// LocalStructureAnalyse: structure tensor + closed-form 2x2 eigendecomposition.
// x: (16,1,1536,1536) fp32.  Out: 6 planes (16,1536,1536) fp32 concatenated:
//   lambda1(ReLU), lambda2, e11, e12, e21, e22.
//
// R4: single-barrier design. Stage x tile in LDS; each thread computes its own
// 6 register column-sums (vertical 3-tap of gradient products) for its 4 output
// px, then horizontal 3-tap + eig + float4 nt stores. Interior blocks (82%)
// take a conditional-free fast path. LDS = Xs only (10.3 KB).

typedef float f32x4 __attribute__((ext_vector_type(4)));
typedef float f32x2 __attribute__((ext_vector_type(2)));

constexpr int N_ = 16, H = 1536, W = 1536;
constexpr int TH = 16, TW = 128;      // output tile
constexpr int XR = TH + 3;            // x rows staged: ti0-2 .. ti0+16
constexpr int XQ = 34;                // float4s per x row: cols tj0-4 .. tj0+131
constexpr int XC = XQ * 4;            // 136

__device__ __forceinline__ void eig_emit(
    const float Sxx[6], const float Sxy[6], const float Syy[6],
    f32x4& o_l1, f32x4& o_l2, f32x4& o_e11, f32x4& o_e12, f32x4& o_e21, f32x4& o_e22) {
    const float inv9 = 1.0f / 9.0f;
#pragma unroll
    for (int k = 0; k < 4; ++k) {
        const float Axx = (Sxx[k] + Sxx[k + 1] + Sxx[k + 2]) * inv9;
        const float Axy = (Sxy[k] + Sxy[k + 1] + Sxy[k + 2]) * inv9;
        const float Ayy = (Syy[k] + Syy[k + 1] + Syy[k + 2]) * inv9;

        const float T  = Axx + Ayy;
        const float Dd = Axx * Ayy - Axy * Axy;
        const float s  = sqrtf(fabsf(T * T * 0.25f - Dd));
        const float l1 = T * 0.5f + s;
        const float l2 = T * 0.5f - s;

        float e11 = l1 - Ayy, e12 = Axy;
        float e21 = l2 - Ayy, e22 = Axy;
        const bool small = fabsf(Axy) < 1e-9f;
        e11 = small ? 1.0f : e11;
        e12 = small ? 0.0f : e12;
        e21 = small ? 0.0f : e21;
        e22 = small ? 1.0f : e22;

        const bool lt = fabsf(l1) < fabsf(l2);
        o_l1[k]  = fmaxf(lt ? l1 : l2, 0.0f);  // ReLU only lambda1 (ref typo)
        o_l2[k]  = lt ? l2 : l1;
        o_e11[k] = lt ? e11 : e21;
        o_e12[k] = lt ? e12 : e22;
        o_e21[k] = lt ? e21 : e11;
        o_e22[k] = lt ? e22 : e12;
    }
}

__global__ __launch_bounds__(256, 5)
void lsa_kernel(const float* __restrict__ x, float* __restrict__ out) {
    __shared__ float Xs[XR][XC];

    const int tj0 = blockIdx.x * TW;
    const int ti0 = blockIdx.y * TH;
    const int n   = blockIdx.z;
    const float* __restrict__ xn = x + (size_t)n * (H * W);
    const int tid  = threadIdx.x;
    const int rsub = tid >> 5;        // 0..7
    const int csub = tid & 31;        // 0..31
    const int cj   = 4 * csub;        // 0..124

    // ---- stage x tile: rows ti0-2..ti0+16, cols tj0-4..tj0+131 (zero-pad OOB) ----
    for (int rr = rsub; rr < XR; rr += 8) {
        const int p = ti0 - 2 + rr;
        const float* rowp = xn + (size_t)p * W;
        const bool prow = (p >= 0) & (p < H);
        for (int cq = csub; cq < XQ; cq += 32) {
            const int qb = tj0 - 4 + 4 * cq;
            f32x4 v;
            if (prow && qb >= 0 && qb + 3 < W) {
                v = *reinterpret_cast<const f32x4*>(rowp + qb);
            } else {
                v.x = (prow && qb + 0 >= 0 && qb + 0 < W) ? rowp[qb + 0] : 0.f;
                v.y = (prow && qb + 1 >= 0 && qb + 1 < W) ? rowp[qb + 1] : 0.f;
                v.z = (prow && qb + 2 >= 0 && qb + 2 < W) ? rowp[qb + 2] : 0.f;
                v.w = (prow && qb + 3 >= 0 && qb + 3 < W) ? rowp[qb + 3] : 0.f;
            }
            *reinterpret_cast<f32x4*>(&Xs[rr][4 * cq]) = v;
        }
    }
    __syncthreads();

    const size_t HW = (size_t)H * W;
    const size_t PLANE = (size_t)N_ * HW;
    float* const ob = out + (size_t)n * HW + (size_t)tj0 + cj;

    // Interior test: all x accesses for this block are in-image and no q==0/p==0 mirror.
    const bool interior = (ti0 >= 2) & (ti0 <= H - TH - 1) & (tj0 >= 2) & (tj0 <= W - TW - 2);

    if (interior) {
#pragma unroll
        for (int rv = 0; rv < 2; ++rv) {
            const int rr = rsub + 8 * rv;     // output row in tile; abs p0 = ti0+rr
            // x window: Xs rows rr..rr+3 (abs p0-2..p0+1), cols cj+2..cj+8 (abs q0-2..q0+4)
            float xv[4][7];
#pragma unroll
            for (int dr = 0; dr < 4; ++dr) {
                const f32x2 a = *reinterpret_cast<const f32x2*>(&Xs[rr + dr][cj + 2]);
                const f32x4 b = *reinterpret_cast<const f32x4*>(&Xs[rr + dr][cj + 4]);
                xv[dr][0] = a.x; xv[dr][1] = a.y;
                xv[dr][2] = b.x; xv[dr][3] = b.y; xv[dr][4] = b.z; xv[dr][5] = b.w;
                xv[dr][6] = Xs[rr + dr][cj + 8];
            }
            // register column-sums for q = q0-1 .. q0+4
            float Sxx[6], Sxy[6], Syy[6];
#pragma unroll
            for (int m = 0; m < 6; ++m) {
                float sxx = 0.f, sxy = 0.f, syy = 0.f;
#pragma unroll
                for (int d = 0; d < 3; ++d) {     // tap rows p0-1..p0+1
                    const float xc = xv[d + 1][m + 1];
                    const float xl = xv[d + 1][m];      // x(p, q-1)
                    const float xu = xv[d][m + 1];      // x(p-1, q)
                    const float gx = xl - xc;
                    const float gy = xu - xc;
                    sxx = fmaf(gx, gx, sxx);
                    sxy = fmaf(gx, gy, sxy);
                    syy = fmaf(gy, gy, syy);
                }
                Sxx[m] = sxx; Sxy[m] = sxy; Syy[m] = syy;
            }
            f32x4 o1, o2, o3, o4, o5, o6;
            eig_emit(Sxx, Sxy, Syy, o1, o2, o3, o4, o5, o6);
            float* op = ob + (size_t)(ti0 + rr) * W;
            __builtin_nontemporal_store(o1, reinterpret_cast<f32x4*>(op));
            __builtin_nontemporal_store(o2, reinterpret_cast<f32x4*>(op + PLANE));
            __builtin_nontemporal_store(o3, reinterpret_cast<f32x4*>(op + 2 * PLANE));
            __builtin_nontemporal_store(o4, reinterpret_cast<f32x4*>(op + 3 * PLANE));
            __builtin_nontemporal_store(o5, reinterpret_cast<f32x4*>(op + 4 * PLANE));
            __builtin_nontemporal_store(o6, reinterpret_cast<f32x4*>(op + 5 * PLANE));
        }
    } else {
#pragma unroll
        for (int rv = 0; rv < 2; ++rv) {
            const int rr = rsub + 8 * rv;
            float Sxx[6], Sxy[6], Syy[6];
#pragma unroll
            for (int m = 0; m < 6; ++m) {
                const int q = tj0 + cj - 1 + m;
                float sxx = 0.f, sxy = 0.f, syy = 0.f;
                if (q >= 0 && q < W) {
                    const int cc = cj + m + 3;          // Xs col for abs col q
#pragma unroll
                    for (int d = 0; d < 3; ++d) {
                        const int p = ti0 + rr - 1 + d;
                        if (p >= 0 && p < H) {
                            const int RR = rr + d + 1;  // Xs row for abs row p
                            const float xc = Xs[RR][cc];
                            const float xl = (q == 0) ? Xs[RR][cc + 1] : Xs[RR][cc - 1];
                            const float xu = (p == 0) ? Xs[RR + 1][cc] : Xs[RR - 1][cc];
                            const float gx = xl - xc;
                            const float gy = xu - xc;
                            sxx = fmaf(gx, gx, sxx);
                            sxy = fmaf(gx, gy, sxy);
                            syy = fmaf(gy, gy, syy);
                        }
                    }
                }
                Sxx[m] = sxx; Sxy[m] = sxy; Syy[m] = syy;
            }
            f32x4 o1, o2, o3, o4, o5, o6;
            eig_emit(Sxx, Sxy, Syy, o1, o2, o3, o4, o5, o6);
            float* op = ob + (size_t)(ti0 + rr) * W;
            __builtin_nontemporal_store(o1, reinterpret_cast<f32x4*>(op));
            __builtin_nontemporal_store(o2, reinterpret_cast<f32x4*>(op + PLANE));
            __builtin_nontemporal_store(o3, reinterpret_cast<f32x4*>(op + 2 * PLANE));
            __builtin_nontemporal_store(o4, reinterpret_cast<f32x4*>(op + 3 * PLANE));
            __builtin_nontemporal_store(o5, reinterpret_cast<f32x4*>(op + 4 * PLANE));
            __builtin_nontemporal_store(o6, reinterpret_cast<f32x4*>(op + 5 * PLANE));
        }
    }
}

extern "C" void kernel_launch(void* const* d_in, const int* in_sizes, int n_in,
                              void* d_out, int out_size, void* d_ws, size_t ws_size,
                              hipStream_t stream) {
    const float* x = (const float*)d_in[0];
    // d_in[1] is the 3x3 weight, fixed to 1/9 by setup -> folded into inv9.
    float* out = (float*)d_out;

    dim3 grid(W / TW, H / TH, N_);   // 12 x 96 x 16
    dim3 block(256);
    lsa_kernel<<<grid, block, 0, stream>>>(x, out);
}

// Round 5
// 179.766 us; speedup vs baseline: 1.7148x; 1.0121x over previous
//
#include <hip/hip_runtime.h>

// LocalStructureAnalyse: structure tensor + closed-form 2x2 eigendecomposition.
// x: (16,1,1536,1536) fp32.  Out: 6 planes (16,1536,1536) fp32 concatenated:
//   lambda1(ReLU), lambda2, e11, e12, e21, e22.
//
// R5: no LDS, no barrier. Each thread owns 4 px of one row; reads its 4x8
// x-window straight from global (L1/L2 serve the halo overlap; x fits in L3),
// computes register column-sums + eig, stores 6 f32x4 nontemporal.
// Per-lane interior predicate; guarded scalar path only for edge lanes.

typedef float f32x4 __attribute__((ext_vector_type(4)));
typedef float f32x2 __attribute__((ext_vector_type(2)));

constexpr int N_ = 16, H = 1536, W = 1536;

__global__ __launch_bounds__(256, 4)
void lsa_kernel(const float* __restrict__ x, float* __restrict__ out) {
    const int tid  = threadIdx.x;
    const int rsub = tid >> 6;          // 0..3 (one wave per row)
    const int csub = tid & 63;          // 0..63
    const int ti0  = blockIdx.y * 4;
    const int tj0  = blockIdx.x * 256;
    const int n    = blockIdx.z;
    const int p0   = ti0 + rsub;        // output row
    const int q0   = tj0 + 4 * csub;    // first output col (16B aligned)

    const size_t HW = (size_t)H * W;
    const size_t PLANE = (size_t)N_ * HW;
    const float* __restrict__ xn = x + (size_t)n * HW;

    float Sxx[6], Sxy[6], Syy[6];
    const bool interior = (p0 >= 2) & (p0 <= H - 2) & (q0 >= 2) & (q0 <= W - 6);

    if (interior) {
        // window rows p0-2..p0+1, cols q0-2..q0+5 (8 floats, aligned 8/16/8 loads)
        float xv[4][8];
        const float* rp = xn + (size_t)(p0 - 2) * W + (q0 - 2);
#pragma unroll
        for (int d = 0; d < 4; ++d) {
            const f32x2 a = *reinterpret_cast<const f32x2*>(rp);
            const f32x4 b = *reinterpret_cast<const f32x4*>(rp + 2);
            const f32x2 c = *reinterpret_cast<const f32x2*>(rp + 6);
            xv[d][0] = a.x; xv[d][1] = a.y;
            xv[d][2] = b.x; xv[d][3] = b.y; xv[d][4] = b.z; xv[d][5] = b.w;
            xv[d][6] = c.x; xv[d][7] = c.y;
            rp += W;
        }
#pragma unroll
        for (int m = 0; m < 6; ++m) {
            float sxx = 0.f, sxy = 0.f, syy = 0.f;
#pragma unroll
            for (int d = 0; d < 3; ++d) {          // tap rows p0-1..p0+1
                const float xc = xv[d + 1][m + 1];
                const float xl = xv[d + 1][m];     // x(p, q-1)
                const float xu = xv[d][m + 1];     // x(p-1, q)
                const float gx = xl - xc;
                const float gy = xu - xc;
                sxx = fmaf(gx, gx, sxx);
                sxy = fmaf(gx, gy, sxy);
                syy = fmaf(gy, gy, syy);
            }
            Sxx[m] = sxx; Sxy[m] = sxy; Syy[m] = syy;
        }
    } else {
        // guarded scalar path (edge lanes only, ~0.5%)
#pragma unroll
        for (int m = 0; m < 6; ++m) {
            const int q = q0 - 1 + m;
            float sxx = 0.f, sxy = 0.f, syy = 0.f;
            if (q >= 0 && q < W) {
#pragma unroll
                for (int d = 0; d < 3; ++d) {
                    const int p = p0 - 1 + d;
                    if (p >= 0 && p < H) {
                        const float* prow = xn + (size_t)p * W;
                        const float xc = prow[q];
                        const float xl = (q == 0) ? prow[1] : prow[q - 1];
                        const float xu = (p == 0) ? xn[(size_t)W + q] : prow[q - W];
                        const float gx = xl - xc;
                        const float gy = xu - xc;
                        sxx = fmaf(gx, gx, sxx);
                        sxy = fmaf(gx, gy, sxy);
                        syy = fmaf(gy, gy, syy);
                    }
                }
            }
            Sxx[m] = sxx; Sxy[m] = sxy; Syy[m] = syy;
        }
    }

    // horizontal 3-tap + eig for 4 px
    f32x4 o_l1, o_l2, o_e11, o_e12, o_e21, o_e22;
    const float inv9 = 1.0f / 9.0f;
#pragma unroll
    for (int k = 0; k < 4; ++k) {
        const float Axx = (Sxx[k] + Sxx[k + 1] + Sxx[k + 2]) * inv9;
        const float Axy = (Sxy[k] + Sxy[k + 1] + Sxy[k + 2]) * inv9;
        const float Ayy = (Syy[k] + Syy[k + 1] + Syy[k + 2]) * inv9;

        const float T  = Axx + Ayy;
        const float Dd = Axx * Ayy - Axy * Axy;
        const float s  = sqrtf(fabsf(T * T * 0.25f - Dd));
        const float l1 = T * 0.5f + s;
        const float l2 = T * 0.5f - s;

        float e11 = l1 - Ayy, e12 = Axy;
        float e21 = l2 - Ayy, e22 = Axy;
        const bool small = fabsf(Axy) < 1e-9f;
        e11 = small ? 1.0f : e11;
        e12 = small ? 0.0f : e12;
        e21 = small ? 0.0f : e21;
        e22 = small ? 1.0f : e22;

        const bool lt = fabsf(l1) < fabsf(l2);
        o_l1[k]  = fmaxf(lt ? l1 : l2, 0.0f);   // ReLU only lambda1 (ref typo)
        o_l2[k]  = lt ? l2 : l1;
        o_e11[k] = lt ? e11 : e21;
        o_e12[k] = lt ? e12 : e22;
        o_e21[k] = lt ? e21 : e11;
        o_e22[k] = lt ? e22 : e12;
    }

    float* op = out + (size_t)n * HW + (size_t)p0 * W + q0;
    __builtin_nontemporal_store(o_l1,  reinterpret_cast<f32x4*>(op));
    __builtin_nontemporal_store(o_l2,  reinterpret_cast<f32x4*>(op + PLANE));
    __builtin_nontemporal_store(o_e11, reinterpret_cast<f32x4*>(op + 2 * PLANE));
    __builtin_nontemporal_store(o_e12, reinterpret_cast<f32x4*>(op + 3 * PLANE));
    __builtin_nontemporal_store(o_e21, reinterpret_cast<f32x4*>(op + 4 * PLANE));
    __builtin_nontemporal_store(o_e22, reinterpret_cast<f32x4*>(op + 5 * PLANE));
}

extern "C" void kernel_launch(void* const* d_in, const int* in_sizes, int n_in,
                              void* d_out, int out_size, void* d_ws, size_t ws_size,
                              hipStream_t stream) {
    const float* x = (const float*)d_in[0];
    // d_in[1] is the 3x3 weight, fixed to 1/9 by setup -> folded into inv9.
    float* out = (float*)d_out;

    dim3 grid(W / 256, H / 4, N_);   // 6 x 384 x 16
    dim3 block(256);
    lsa_kernel<<<grid, block, 0, stream>>>(x, out);
}

// Round 6
// 171.612 us; speedup vs baseline: 1.7963x; 1.0475x over previous
//
#include <hip/hip_runtime.h>

// LocalStructureAnalyse: structure tensor + closed-form 2x2 eigendecomposition.
// x: (16,1,1536,1536) fp32.  Out: 6 planes (16,1536,1536) fp32 concatenated:
//   lambda1(ReLU), lambda2, e11, e12, e21, e22.
//
// R6: no LDS/barrier (R5) + 2 output rows per thread from one 5-row register
// window (shares 2 of 4 gradient-product rows between the two vertical sums;
// loads per 8 px: 24 -> 15) + raw v_sqrt_f32. 6x f32x4 nt stores per row.

typedef float f32x4 __attribute__((ext_vector_type(4)));
typedef float f32x2 __attribute__((ext_vector_type(2)));

constexpr int N_ = 16, H = 1536, W = 1536;

__device__ __forceinline__ void eig_row(
    const float S_xx[6], const float S_xy[6], const float S_yy[6],
    float* __restrict__ op, size_t PLANE) {
    f32x4 o_l1, o_l2, o_e11, o_e12, o_e21, o_e22;
    const float inv9 = 1.0f / 9.0f;
#pragma unroll
    for (int k = 0; k < 4; ++k) {
        const float Axx = (S_xx[k] + S_xx[k + 1] + S_xx[k + 2]) * inv9;
        const float Axy = (S_xy[k] + S_xy[k + 1] + S_xy[k + 2]) * inv9;
        const float Ayy = (S_yy[k] + S_yy[k + 1] + S_yy[k + 2]) * inv9;

        const float T  = Axx + Ayy;
        const float Dd = Axx * Ayy - Axy * Axy;
        const float s  = __builtin_amdgcn_sqrtf(fabsf(T * T * 0.25f - Dd));
        const float l1 = T * 0.5f + s;
        const float l2 = T * 0.5f - s;

        float e11 = l1 - Ayy, e12 = Axy;
        float e21 = l2 - Ayy, e22 = Axy;
        const bool small = fabsf(Axy) < 1e-9f;
        e11 = small ? 1.0f : e11;
        e12 = small ? 0.0f : e12;
        e21 = small ? 0.0f : e21;
        e22 = small ? 1.0f : e22;

        const bool lt = fabsf(l1) < fabsf(l2);
        o_l1[k]  = fmaxf(lt ? l1 : l2, 0.0f);   // ReLU only lambda1 (ref typo)
        o_l2[k]  = lt ? l2 : l1;
        o_e11[k] = lt ? e11 : e21;
        o_e12[k] = lt ? e12 : e22;
        o_e21[k] = lt ? e21 : e11;
        o_e22[k] = lt ? e22 : e12;
    }
    __builtin_nontemporal_store(o_l1,  reinterpret_cast<f32x4*>(op));
    __builtin_nontemporal_store(o_l2,  reinterpret_cast<f32x4*>(op + PLANE));
    __builtin_nontemporal_store(o_e11, reinterpret_cast<f32x4*>(op + 2 * PLANE));
    __builtin_nontemporal_store(o_e12, reinterpret_cast<f32x4*>(op + 3 * PLANE));
    __builtin_nontemporal_store(o_e21, reinterpret_cast<f32x4*>(op + 4 * PLANE));
    __builtin_nontemporal_store(o_e22, reinterpret_cast<f32x4*>(op + 5 * PLANE));
}

__global__ __launch_bounds__(256, 4)
void lsa_kernel(const float* __restrict__ x, float* __restrict__ out) {
    const int tid  = threadIdx.x;
    const int rsub = tid >> 6;          // 0..3
    const int csub = tid & 63;          // 0..63
    const int P0   = blockIdx.y * 8 + 2 * rsub;   // first of 2 output rows
    const int q0   = blockIdx.x * 256 + 4 * csub; // first output col (16B aligned)
    const int n    = blockIdx.z;

    const size_t HW = (size_t)H * W;
    const size_t PLANE = (size_t)N_ * HW;
    const float* __restrict__ xn = x + (size_t)n * HW;

    float S0xx[6], S0xy[6], S0yy[6];    // vertical sums for output row P0
    float S1xx[6], S1xy[6], S1yy[6];    // vertical sums for output row P0+1

    const bool interior = (P0 >= 2) & (P0 <= H - 3) & (q0 >= 2) & (q0 <= W - 6);

    if (interior) {
        // x window rows P0-2..P0+2, cols q0-2..q0+5 (aligned 8/16/8 loads)
        float xv[5][8];
        const float* rp = xn + (size_t)(P0 - 2) * W + (q0 - 2);
#pragma unroll
        for (int d = 0; d < 5; ++d) {
            const f32x2 a = *reinterpret_cast<const f32x2*>(rp);
            const f32x4 b = *reinterpret_cast<const f32x4*>(rp + 2);
            const f32x2 c = *reinterpret_cast<const f32x2*>(rp + 6);
            xv[d][0] = a.x; xv[d][1] = a.y;
            xv[d][2] = b.x; xv[d][3] = b.y; xv[d][4] = b.z; xv[d][5] = b.w;
            xv[d][6] = c.x; xv[d][7] = c.y;
            rp += W;
        }
#pragma unroll
        for (int m = 0; m < 6; ++m) {
            S0xx[m] = 0.f; S0xy[m] = 0.f; S0yy[m] = 0.f;
            S1xx[m] = 0.f; S1xy[m] = 0.f; S1yy[m] = 0.f;
        }
        // product tap rows t=0..3 -> abs rows P0-1..P0+2
#pragma unroll
        for (int t = 0; t < 4; ++t) {
#pragma unroll
            for (int m = 0; m < 6; ++m) {
                const float xc = xv[t + 1][m + 1];
                const float xl = xv[t + 1][m];      // x(p, q-1)
                const float xu = xv[t][m + 1];      // x(p-1, q)
                const float gx = xl - xc;
                const float gy = xu - xc;
                const float pxx = gx * gx;
                const float pxy = gx * gy;
                const float pyy = gy * gy;
                if (t < 3) { S0xx[m] += pxx; S0xy[m] += pxy; S0yy[m] += pyy; }
                if (t > 0) { S1xx[m] += pxx; S1xy[m] += pxy; S1yy[m] += pyy; }
            }
        }
    } else {
        // guarded scalar path (edge lanes only)
#pragma unroll
        for (int r = 0; r < 2; ++r) {
            float* Sxx = r ? S1xx : S0xx;
            float* Sxy = r ? S1xy : S0xy;
            float* Syy = r ? S1yy : S0yy;
            const int pr = P0 + r;
#pragma unroll
            for (int m = 0; m < 6; ++m) {
                const int q = q0 - 1 + m;
                float sxx = 0.f, sxy = 0.f, syy = 0.f;
                if (q >= 0 && q < W) {
#pragma unroll
                    for (int d = 0; d < 3; ++d) {
                        const int p = pr - 1 + d;
                        if (p >= 0 && p < H) {
                            const float* prow = xn + (size_t)p * W;
                            const float xc = prow[q];
                            const float xl = (q == 0) ? prow[1] : prow[q - 1];
                            const float xu = (p == 0) ? xn[(size_t)W + q] : prow[q - W];
                            const float gx = xl - xc;
                            const float gy = xu - xc;
                            sxx = fmaf(gx, gx, sxx);
                            sxy = fmaf(gx, gy, sxy);
                            syy = fmaf(gy, gy, syy);
                        }
                    }
                }
                Sxx[m] = sxx; Sxy[m] = sxy; Syy[m] = syy;
            }
        }
    }

    float* op = out + (size_t)n * HW + (size_t)P0 * W + q0;
    eig_row(S0xx, S0xy, S0yy, op, PLANE);
    eig_row(S1xx, S1xy, S1yy, op + W, PLANE);
}

extern "C" void kernel_launch(void* const* d_in, const int* in_sizes, int n_in,
                              void* d_out, int out_size, void* d_ws, size_t ws_size,
                              hipStream_t stream) {
    const float* x = (const float*)d_in[0];
    // d_in[1] is the 3x3 weight, fixed to 1/9 by setup -> folded into inv9.
    float* out = (float*)d_out;

    dim3 grid(W / 256, H / 8, N_);   // 6 x 192 x 16
    dim3 block(256);
    lsa_kernel<<<grid, block, 0, stream>>>(x, out);
}